// Round 10
// baseline (54.749 us; speedup 1.0000x reference)
//
#include <hip/hip_runtime.h>

#define BATCH 256
#define IN1   10240
#define NU    32
#define SPLITS 128
#define STRIPE (IN1 / SPLITS)   // 80 i per block
#define BBLK  16                // b per block (4 per wave, 2 per thread)
#define NGRP  (STRIPE / 4)      // 20 groups of 4 i
#define LOG2E 1.4426950408889634f

// ---------------- Kernel 0: pack transformed params -----------------------
// Ppk[i*32+u] = {A, C, W, W*erev};  A = iw*ssig*log2e, C = (smu-ib)*ssig*log2e
__global__ __launch_bounds__(256) void ltc_pack(
    const float* __restrict__ iw, const float* __restrict__ ibias,
    const float* __restrict__ smu, const float* __restrict__ ssig,
    const float* __restrict__ sW, const float* __restrict__ serev,
    float4* __restrict__ Ppk)
{
    const int idx = blockIdx.x * 256 + threadIdx.x;   // 0..IN1*NU-1
    const int i = idx >> 5;
    const float sg = ssig[idx] * LOG2E;
    const float A  = sg * iw[i];
    const float C  = (smu[idx] - ibias[i]) * sg;
    const float w  = sW[idx];
    Ppk[idx] = make_float4(A, C, w, w * serev[idx]);
}

// ---------------- Kernel 1: sensory partial sums --------------------------
// grid = (16 b-tiles, 128 i-stripes), block = 256 = 8 waves-worth of work
// at MINIMAL register state: thread owns 2 batches, 4 accumulators.
// __launch_bounds__(256, 8) caps VGPR at 64 -> 8 waves/SIMD (the occupancy
// cliff halves waves/SIMD above 64 VGPR). 2048 blocks x 4 waves = 8192
// waves = 8/SIMD chip-wide; latency hidden by TLP, not manual pipelining.
__global__ __launch_bounds__(256, 8) void ltc_sensory_partial(
    const float* __restrict__ x,
    const float4* __restrict__ Ppk,
    float2* __restrict__ part)
{
    const int tid = threadIdx.x;
    const int u   = tid & 31;
    const int il  = (tid >> 5) & 1;
    const int wv  = tid >> 6;
    const int bt  = blockIdx.x;          // 0..15
    const int s   = blockIdx.y;          // 0..SPLITS-1
    const int i0  = s * STRIPE;
    const int b0  = bt * BBLK + wv * 4 + il * 2;

    const float* xr0 = x + (size_t)(b0 + 0) * IN1 + i0;
    const float* xr1 = x + (size_t)(b0 + 1) * IN1 + i0;
    const float4* pb = Ppk + (size_t)i0 * NU + u;

    float an0 = 0.f, ad0 = 0.f, an1 = 0.f, ad1 = 0.f;

#pragma unroll 2
    for (int g = 0; g < NGRP; ++g) {
        const float4 p0 = pb[(size_t)g * 4 * NU + 0 * NU];
        const float4 p1 = pb[(size_t)g * 4 * NU + 1 * NU];
        const float4 p2 = pb[(size_t)g * 4 * NU + 2 * NU];
        const float4 p3 = pb[(size_t)g * 4 * NU + 3 * NU];
        const float4 x0 = *(const float4*)(xr0 + g * 4);
        const float4 x1 = *(const float4*)(xr1 + g * 4);

        float e, r;
        e = __builtin_amdgcn_exp2f(p0.y - x0.x * p0.x);
        r = __builtin_amdgcn_rcpf(1.0f + e);
        ad0 = fmaf(p0.z, r, ad0); an0 = fmaf(p0.w, r, an0);
        e = __builtin_amdgcn_exp2f(p0.y - x1.x * p0.x);
        r = __builtin_amdgcn_rcpf(1.0f + e);
        ad1 = fmaf(p0.z, r, ad1); an1 = fmaf(p0.w, r, an1);

        e = __builtin_amdgcn_exp2f(p1.y - x0.y * p1.x);
        r = __builtin_amdgcn_rcpf(1.0f + e);
        ad0 = fmaf(p1.z, r, ad0); an0 = fmaf(p1.w, r, an0);
        e = __builtin_amdgcn_exp2f(p1.y - x1.y * p1.x);
        r = __builtin_amdgcn_rcpf(1.0f + e);
        ad1 = fmaf(p1.z, r, ad1); an1 = fmaf(p1.w, r, an1);

        e = __builtin_amdgcn_exp2f(p2.y - x0.z * p2.x);
        r = __builtin_amdgcn_rcpf(1.0f + e);
        ad0 = fmaf(p2.z, r, ad0); an0 = fmaf(p2.w, r, an0);
        e = __builtin_amdgcn_exp2f(p2.y - x1.z * p2.x);
        r = __builtin_amdgcn_rcpf(1.0f + e);
        ad1 = fmaf(p2.z, r, ad1); an1 = fmaf(p2.w, r, an1);

        e = __builtin_amdgcn_exp2f(p3.y - x0.w * p3.x);
        r = __builtin_amdgcn_rcpf(1.0f + e);
        ad0 = fmaf(p3.z, r, ad0); an0 = fmaf(p3.w, r, an0);
        e = __builtin_amdgcn_exp2f(p3.y - x1.w * p3.x);
        r = __builtin_amdgcn_rcpf(1.0f + e);
        ad1 = fmaf(p3.z, r, ad1); an1 = fmaf(p3.w, r, an1);
    }

    float2* po = part + (size_t)s * BATCH * NU;
    po[(size_t)(b0 + 0) * NU + u] = make_float2(an0, ad0);
    po[(size_t)(b0 + 1) * NU + u] = make_float2(an1, ad1);
}

// ---------------- Kernel 2: reduce split partials -------------------------
__global__ __launch_bounds__(256) void ltc_reduce(
    const float2* __restrict__ part, int nsplit, float2* __restrict__ S)
{
    const int tid = threadIdx.x;
    const int b   = blockIdx.x;
    const int u   = tid & 31;
    const int sl  = tid >> 5;

    __shared__ float sred[8][NU][2];

    float sn = 0.f, sd = 0.f;
#pragma unroll 8
    for (int s = sl; s < nsplit; s += 8) {
        const float2 p = part[((size_t)s * BATCH + b) * NU + u];
        sn += p.x;
        sd += p.y;
    }
    sred[sl][u][0] = sn;
    sred[sl][u][1] = sd;
    __syncthreads();

    if (tid >= 32) return;
    float Sn = 0.f, Sd = 0.f;
#pragma unroll
    for (int s2 = 0; s2 < 8; ++s2) {
        Sn += sred[s2][u][0];
        Sd += sred[s2][u][1];
    }
    S[(size_t)b * NU + u] = make_float2(Sn, Sd);
}

// ---------------- Kernel 3: unfolds + cell B + output ---------------------
__global__ __launch_bounds__(256) void ltc_unfold(
    const float2* __restrict__ S,
    const float* __restrict__ amu, const float* __restrict__ asig,
    const float* __restrict__ aW,  const float* __restrict__ aerev,
    const float* __restrict__ agleak, const float* __restrict__ avleak,
    const float* __restrict__ acm,
    const float* __restrict__ b_iw, const float* __restrict__ b_ib,
    const float* __restrict__ b_smu, const float* __restrict__ b_ssig,
    const float* __restrict__ b_sW,  const float* __restrict__ b_serev,
    const float* __restrict__ b_mu,  const float* __restrict__ b_sig,
    const float* __restrict__ b_W,   const float* __restrict__ b_erev,
    const float* __restrict__ b_gleak, const float* __restrict__ b_vleak,
    const float* __restrict__ b_cm,
    float* __restrict__ out)
{
    const int tid = threadIdx.x;
    const int u   = tid & 31;
    const int bl  = tid >> 5;
    const int b   = blockIdx.x * 8 + bl;

    __shared__ float pAp[NU*NU], pCp[NU*NU];
    __shared__ float pW[NU*NU],  pWE[NU*NU];

    for (int p = tid; p < NU * NU; p += 256) {
        const float sg = asig[p] * LOG2E;
        pAp[p] = sg;
        pCp[p] = amu[p] * sg;
        const float w = aW[p];
        pW[p]  = w;
        pWE[p] = w * aerev[p];
    }
    __syncthreads();

    const float2 Sv = S[(size_t)b * NU + u];
    const float Sn = Sv.x, Sd = Sv.y;

    const float cmt = acm[u] * 6.0f;
    const float gl  = agleak[u];
    const float gv  = gl * avleak[u];

    float v = 0.f;
    for (int k = 0; k < 6; ++k) {
        float rn = 0.f, rd = 0.f;
#pragma unroll
        for (int j = 0; j < NU; ++j) {
            const float vj = __shfl(v, j, 32);
            const int pi = j * NU + u;
            const float e = __builtin_amdgcn_exp2f(pCp[pi] - vj * pAp[pi]);
            const float r = __builtin_amdgcn_rcpf(1.0f + e);
            rn = fmaf(pWE[pi], r, rn);
            rd = fmaf(pW[pi],  r, rd);
        }
        const float num = cmt * v + gv + rn + Sn;
        const float den = cmt + gl + rd + Sd;
        v = num / den;
    }

    const float x2  = v * b_iw[u] + b_ib[u];
    const float e2  = __builtin_amdgcn_exp2f((b_smu[u] - x2) * b_ssig[u] * LOG2E);
    const float s2v = b_sW[u] * __builtin_amdgcn_rcpf(1.0f + e2);
    float wn = s2v * b_serev[u];
    float wd = s2v;
#pragma unroll
    for (int m = 16; m >= 1; m >>= 1) {
        wn += __shfl_xor(wn, m, 32);
        wd += __shfl_xor(wd, m, 32);
    }

    const float bcmt = b_cm[0] * 6.0f;
    const float bgl  = b_gleak[0];
    const float bgv  = bgl * b_vleak[0];
    const float bmu  = b_mu[0], bsig = b_sig[0], bW = b_W[0], berev = b_erev[0];
    float v2 = 0.f;
#pragma unroll
    for (int k = 0; k < 6; ++k) {
        const float ee = __builtin_amdgcn_exp2f((bmu - v2) * bsig * LOG2E);
        const float ws = bW * __builtin_amdgcn_rcpf(1.0f + ee);
        const float num = bcmt * v2 + bgv + ws * berev + wn;
        const float den = bcmt + bgl + ws + wd;
        v2 = num / den;
    }

    if (u == 0)
        out[b] = 1.0f / (1.0f + __builtin_amdgcn_exp2f(-v2 * LOG2E));
}

extern "C" void kernel_launch(void* const* d_in, const int* in_sizes, int n_in,
                              void* d_out, int out_size, void* d_ws, size_t ws_size,
                              hipStream_t stream) {
    const float* x       = (const float*)d_in[0];
    const float* a_iw    = (const float*)d_in[1];
    const float* a_ib    = (const float*)d_in[2];
    const float* a_smu   = (const float*)d_in[3];
    const float* a_ssig  = (const float*)d_in[4];
    const float* a_sW    = (const float*)d_in[5];
    const float* a_serev = (const float*)d_in[6];
    const float* a_mu    = (const float*)d_in[7];
    const float* a_sig   = (const float*)d_in[8];
    const float* a_W     = (const float*)d_in[9];
    const float* a_erev  = (const float*)d_in[10];
    const float* a_gleak = (const float*)d_in[11];
    const float* a_vleak = (const float*)d_in[12];
    const float* a_cm    = (const float*)d_in[13];
    const float* b_iw    = (const float*)d_in[14];
    const float* b_ib    = (const float*)d_in[15];
    const float* b_smu   = (const float*)d_in[16];
    const float* b_ssig  = (const float*)d_in[17];
    const float* b_sW    = (const float*)d_in[18];
    const float* b_serev = (const float*)d_in[19];
    const float* b_mu    = (const float*)d_in[20];
    const float* b_sig   = (const float*)d_in[21];
    const float* b_W     = (const float*)d_in[22];
    const float* b_erev  = (const float*)d_in[23];
    const float* b_gleak = (const float*)d_in[24];
    const float* b_vleak = (const float*)d_in[25];
    const float* b_cm    = (const float*)d_in[26];
    float* out = (float*)d_out;

    float4* Ppk  = (float4*)d_ws;                                // 5.24 MB
    float2* part = (float2*)(Ppk + (size_t)IN1 * NU);            // 8.39 MB
    float2* Sarr = part + (size_t)SPLITS * BATCH * NU;           // 16 KB

    ltc_pack<<<(IN1 * NU) / 256, 256, 0, stream>>>(
        a_iw, a_ib, a_smu, a_ssig, a_sW, a_serev, Ppk);

    dim3 g1(BATCH / BBLK, SPLITS);
    ltc_sensory_partial<<<g1, 256, 0, stream>>>(x, Ppk, part);

    ltc_reduce<<<BATCH, 256, 0, stream>>>(part, SPLITS, Sarr);

    ltc_unfold<<<BATCH / 8, 256, 0, stream>>>(
        Sarr,
        a_mu, a_sig, a_W, a_erev, a_gleak, a_vleak, a_cm,
        b_iw, b_ib, b_smu, b_ssig, b_sW, b_serev,
        b_mu, b_sig, b_W, b_erev, b_gleak, b_vleak, b_cm,
        out);
}

// Round 11
// 49.236 us; speedup vs baseline: 1.1120x; 1.1120x over previous
//
#include <hip/hip_runtime.h>

#define BATCH 256
#define IN1   10240
#define NU    32
#define SPLITS 256
#define STRIPE (IN1 / SPLITS)   // 40 i per block
#define NPAIR  (STRIPE / 2)     // 20 i-pairs per wave
#define BBLK  64                // batches per block (16 per wave)
#define LOG2E 1.4426950408889634f

// ---------------- Kernel 0: pack transformed params -----------------------
// Ppk[i*32+u] = {A, C, W, W*erev};  A = iw*ssig*log2e, C = (smu-ib)*ssig*log2e
__global__ __launch_bounds__(256) void ltc_pack(
    const float* __restrict__ iw, const float* __restrict__ ibias,
    const float* __restrict__ smu, const float* __restrict__ ssig,
    const float* __restrict__ sW, const float* __restrict__ serev,
    float4* __restrict__ Ppk)
{
    const int idx = blockIdx.x * 256 + threadIdx.x;   // 0..IN1*NU-1
    const int i = idx >> 5;
    const float sg = ssig[idx] * LOG2E;
    const float A  = sg * iw[i];
    const float C  = (smu[idx] - ibias[i]) * sg;
    const float w  = sW[idx];
    Ppk[idx] = make_float4(A, C, w, w * serev[idx]);
}

// ---------------- Kernel 1: sensory partial sums --------------------------
// grid = (4 b-supertiles, 256 stripes). Block: 4 waves x 16 batches = 64 b,
// stripe of 40 i. x staged TRANSPOSED in LDS (xT[i][b]) once per block;
// params stream through L1 exactly once per wave as lane-linear dwordx4
// (lane=(u,bh) -> (2i x 32u) float4 block: 1024B/instr, zero duplication,
// ~1 B per task through the L1 return path -- the R7-R10 bottleneck).
// Thread (u,bh) computes its bh-parity i's for 16 batches; bh halves merged
// with one shfl_xor(32) pass at the end. No cross-wave interaction.
#define SIGQ(q, base) do {                                                \
    float e_, r_;                                                         \
    e_ = __builtin_amdgcn_exp2f(p.y - (q).x * p.x);                       \
    r_ = __builtin_amdgcn_rcpf(1.0f + e_);                                \
    ad[(base)+0] = fmaf(p.z, r_, ad[(base)+0]);                           \
    an[(base)+0] = fmaf(p.w, r_, an[(base)+0]);                           \
    e_ = __builtin_amdgcn_exp2f(p.y - (q).y * p.x);                       \
    r_ = __builtin_amdgcn_rcpf(1.0f + e_);                                \
    ad[(base)+1] = fmaf(p.z, r_, ad[(base)+1]);                           \
    an[(base)+1] = fmaf(p.w, r_, an[(base)+1]);                           \
    e_ = __builtin_amdgcn_exp2f(p.y - (q).z * p.x);                       \
    r_ = __builtin_amdgcn_rcpf(1.0f + e_);                                \
    ad[(base)+2] = fmaf(p.z, r_, ad[(base)+2]);                           \
    an[(base)+2] = fmaf(p.w, r_, an[(base)+2]);                           \
    e_ = __builtin_amdgcn_exp2f(p.y - (q).w * p.x);                       \
    r_ = __builtin_amdgcn_rcpf(1.0f + e_);                                \
    ad[(base)+3] = fmaf(p.z, r_, ad[(base)+3]);                           \
    an[(base)+3] = fmaf(p.w, r_, an[(base)+3]);                           \
} while (0)

__global__ __launch_bounds__(256, 4) void ltc_sensory_partial(
    const float* __restrict__ x,
    const float4* __restrict__ Ppk,
    float2* __restrict__ part)
{
    const int tid  = threadIdx.x;
    const int lane = tid & 63;
    const int u    = tid & 31;
    const int bh   = (tid >> 5) & 1;
    const int w    = tid >> 6;            // wave 0..3: batches w*16..w*16+15
    const int bt   = blockIdx.x;          // 0..3
    const int s    = blockIdx.y;          // 0..SPLITS-1
    const int b0   = bt * BBLK;
    const int i0   = s * STRIPE;

    __shared__ float xT[STRIPE][BBLK];    // 10 KB, xT[i][b]

    // stage x[b0..b0+63][i0..i0+39] transposed (read exactly once chip-wide)
    for (int idx = tid; idx < BBLK * (STRIPE / 4); idx += 256) {
        const int r  = idx & (BBLK - 1);
        const int c4 = idx >> 6;
        const float4 v = *(const float4*)(x + (size_t)(b0 + r) * IN1 + i0 + c4 * 4);
        xT[c4 * 4 + 0][r] = v.x;
        xT[c4 * 4 + 1][r] = v.y;
        xT[c4 * 4 + 2][r] = v.z;
        xT[c4 * 4 + 3][r] = v.w;
    }
    __syncthreads();

    // lane-linear param stream: element (i0 + ip*2 + bh)*32 + u  ==  base + ip*64 + lane
    const float4* pb = Ppk + (size_t)i0 * NU + lane;

    float an[16], ad[16];
#pragma unroll
    for (int k = 0; k < 16; ++k) { an[k] = 0.f; ad[k] = 0.f; }

#pragma unroll 2
    for (int ip = 0; ip < NPAIR; ++ip) {
        const float4 p = pb[ip * 64];                  // 1024B coalesced
        const int il = ip * 2 + bh;                    // this thread's i
        const float4* xrow = (const float4*)&xT[il][w * 16];
        const float4 q0 = xrow[0];
        const float4 q1 = xrow[1];
        const float4 q2 = xrow[2];
        const float4 q3 = xrow[3];
        SIGQ(q0, 0);
        SIGQ(q1, 4);
        SIGQ(q2, 8);
        SIGQ(q3, 12);
    }

    // merge bh parities (deterministic: even-i sum + odd-i sum)
#pragma unroll
    for (int k = 0; k < 16; ++k) {
        an[k] += __shfl_xor(an[k], 32, 64);
        ad[k] += __shfl_xor(ad[k], 32, 64);
    }

    if (bh == 0) {
        float2* po = part + ((size_t)s * BATCH + b0 + w * 16) * NU + u;
#pragma unroll
        for (int k = 0; k < 16; ++k)
            po[(size_t)k * NU] = make_float2(an[k], ad[k]);
    }
}

// ---------------- Kernel 2: reduce split partials -------------------------
__global__ __launch_bounds__(256) void ltc_reduce(
    const float2* __restrict__ part, int nsplit, float2* __restrict__ S)
{
    const int tid = threadIdx.x;
    const int b   = blockIdx.x;
    const int u   = tid & 31;
    const int sl  = tid >> 5;

    __shared__ float sred[8][NU][2];

    float sn = 0.f, sd = 0.f;
#pragma unroll 8
    for (int s = sl; s < nsplit; s += 8) {
        const float2 p = part[((size_t)s * BATCH + b) * NU + u];
        sn += p.x;
        sd += p.y;
    }
    sred[sl][u][0] = sn;
    sred[sl][u][1] = sd;
    __syncthreads();

    if (tid >= 32) return;
    float Sn = 0.f, Sd = 0.f;
#pragma unroll
    for (int s2 = 0; s2 < 8; ++s2) {
        Sn += sred[s2][u][0];
        Sd += sred[s2][u][1];
    }
    S[(size_t)b * NU + u] = make_float2(Sn, Sd);
}

// ---------------- Kernel 3: unfolds + cell B + output ---------------------
__global__ __launch_bounds__(256) void ltc_unfold(
    const float2* __restrict__ S,
    const float* __restrict__ amu, const float* __restrict__ asig,
    const float* __restrict__ aW,  const float* __restrict__ aerev,
    const float* __restrict__ agleak, const float* __restrict__ avleak,
    const float* __restrict__ acm,
    const float* __restrict__ b_iw, const float* __restrict__ b_ib,
    const float* __restrict__ b_smu, const float* __restrict__ b_ssig,
    const float* __restrict__ b_sW,  const float* __restrict__ b_serev,
    const float* __restrict__ b_mu,  const float* __restrict__ b_sig,
    const float* __restrict__ b_W,   const float* __restrict__ b_erev,
    const float* __restrict__ b_gleak, const float* __restrict__ b_vleak,
    const float* __restrict__ b_cm,
    float* __restrict__ out)
{
    const int tid = threadIdx.x;
    const int u   = tid & 31;
    const int bl  = tid >> 5;
    const int b   = blockIdx.x * 8 + bl;

    __shared__ float pAp[NU*NU], pCp[NU*NU];
    __shared__ float pW[NU*NU],  pWE[NU*NU];

    for (int p = tid; p < NU * NU; p += 256) {
        const float sg = asig[p] * LOG2E;
        pAp[p] = sg;
        pCp[p] = amu[p] * sg;
        const float w = aW[p];
        pW[p]  = w;
        pWE[p] = w * aerev[p];
    }
    __syncthreads();

    const float2 Sv = S[(size_t)b * NU + u];
    const float Sn = Sv.x, Sd = Sv.y;

    const float cmt = acm[u] * 6.0f;
    const float gl  = agleak[u];
    const float gv  = gl * avleak[u];

    float v = 0.f;
    for (int k = 0; k < 6; ++k) {
        float rn = 0.f, rd = 0.f;
#pragma unroll
        for (int j = 0; j < NU; ++j) {
            const float vj = __shfl(v, j, 32);
            const int pi = j * NU + u;
            const float e = __builtin_amdgcn_exp2f(pCp[pi] - vj * pAp[pi]);
            const float r = __builtin_amdgcn_rcpf(1.0f + e);
            rn = fmaf(pWE[pi], r, rn);
            rd = fmaf(pW[pi],  r, rd);
        }
        const float num = cmt * v + gv + rn + Sn;
        const float den = cmt + gl + rd + Sd;
        v = num / den;
    }

    const float x2  = v * b_iw[u] + b_ib[u];
    const float e2  = __builtin_amdgcn_exp2f((b_smu[u] - x2) * b_ssig[u] * LOG2E);
    const float s2v = b_sW[u] * __builtin_amdgcn_rcpf(1.0f + e2);
    float wn = s2v * b_serev[u];
    float wd = s2v;
#pragma unroll
    for (int m = 16; m >= 1; m >>= 1) {
        wn += __shfl_xor(wn, m, 32);
        wd += __shfl_xor(wd, m, 32);
    }

    const float bcmt = b_cm[0] * 6.0f;
    const float bgl  = b_gleak[0];
    const float bgv  = bgl * b_vleak[0];
    const float bmu  = b_mu[0], bsig = b_sig[0], bW = b_W[0], berev = b_erev[0];
    float v2 = 0.f;
#pragma unroll
    for (int k = 0; k < 6; ++k) {
        const float ee = __builtin_amdgcn_exp2f((bmu - v2) * bsig * LOG2E);
        const float ws = bW * __builtin_amdgcn_rcpf(1.0f + ee);
        const float num = bcmt * v2 + bgv + ws * berev + wn;
        const float den = bcmt + bgl + ws + wd;
        v2 = num / den;
    }

    if (u == 0)
        out[b] = 1.0f / (1.0f + __builtin_amdgcn_exp2f(-v2 * LOG2E));
}

extern "C" void kernel_launch(void* const* d_in, const int* in_sizes, int n_in,
                              void* d_out, int out_size, void* d_ws, size_t ws_size,
                              hipStream_t stream) {
    const float* x       = (const float*)d_in[0];
    const float* a_iw    = (const float*)d_in[1];
    const float* a_ib    = (const float*)d_in[2];
    const float* a_smu   = (const float*)d_in[3];
    const float* a_ssig  = (const float*)d_in[4];
    const float* a_sW    = (const float*)d_in[5];
    const float* a_serev = (const float*)d_in[6];
    const float* a_mu    = (const float*)d_in[7];
    const float* a_sig   = (const float*)d_in[8];
    const float* a_W     = (const float*)d_in[9];
    const float* a_erev  = (const float*)d_in[10];
    const float* a_gleak = (const float*)d_in[11];
    const float* a_vleak = (const float*)d_in[12];
    const float* a_cm    = (const float*)d_in[13];
    const float* b_iw    = (const float*)d_in[14];
    const float* b_ib    = (const float*)d_in[15];
    const float* b_smu   = (const float*)d_in[16];
    const float* b_ssig  = (const float*)d_in[17];
    const float* b_sW    = (const float*)d_in[18];
    const float* b_serev = (const float*)d_in[19];
    const float* b_mu    = (const float*)d_in[20];
    const float* b_sig   = (const float*)d_in[21];
    const float* b_W     = (const float*)d_in[22];
    const float* b_erev  = (const float*)d_in[23];
    const float* b_gleak = (const float*)d_in[24];
    const float* b_vleak = (const float*)d_in[25];
    const float* b_cm    = (const float*)d_in[26];
    float* out = (float*)d_out;

    float4* Ppk  = (float4*)d_ws;                                // 5.24 MB
    float2* part = (float2*)(Ppk + (size_t)IN1 * NU);            // 16.8 MB
    float2* Sarr = part + (size_t)SPLITS * BATCH * NU;           // 16 KB

    ltc_pack<<<(IN1 * NU) / 256, 256, 0, stream>>>(
        a_iw, a_ib, a_smu, a_ssig, a_sW, a_serev, Ppk);

    dim3 g1(BATCH / BBLK, SPLITS);
    ltc_sensory_partial<<<g1, 256, 0, stream>>>(x, Ppk, part);

    ltc_reduce<<<BATCH, 256, 0, stream>>>(part, SPLITS, Sarr);

    ltc_unfold<<<BATCH / 8, 256, 0, stream>>>(
        Sarr,
        a_mu, a_sig, a_W, a_erev, a_gleak, a_vleak, a_cm,
        b_iw, b_ib, b_smu, b_ssig, b_sW, b_serev,
        b_mu, b_sig, b_W, b_erev, b_gleak, b_vleak, b_cm,
        out);
}